// Round 13
// baseline (13.280 us; speedup 1.0000x reference)
//
#include <hip/hip_runtime.h>
#include <hip/hip_fp16.h>

// ComplexMixture: B=32, S=128, N=256
// Or[b,n,m] = sum_s w[b,s]*(r[b,s,n]*r[b,s,m] + i[b,s,n]*i[b,s,m])
// Oi[b,n,m] = sum_s w[b,s]*(i[b,s,n]*r[b,s,m] - r[b,s,n]*i[b,s,m])
//
// R13 = R12 staging/barriers + 32x32x16 MFMA (halves LDS fragment bytes per
// FLOP: 384 -> 256 b128/CU) + wave-split tiles: waves 0-3 own tile tj1,
// waves 4-7 own tile tj2. Waves 4-7 cvt/write B2 during tile-1 MFMA; after
// the counted barrier, tile-2 MFMA overlaps tile-1's store drain.
// Proven swizzle slot = chunk ^ ((row>>1)&7); 32-row b128 reads stay
// bank-uniform (lo/hi lane chunks are XOR partners in one 8-slot group).
// 256 blocks x 512 thr, LDS 96 KB, XCD-grouped bid swizzle.

constexpr int B = 32, S = 128, N = 256;

typedef _Float16 f16x8  __attribute__((ext_vector_type(8)));
typedef float    f32x16 __attribute__((ext_vector_type(16)));

union F16x8 { f16x8 v; __half2 h2[4]; };

#define MFMA32(a, bv, c) __builtin_amdgcn_mfma_f32_32x32x16_f16((a), (bv), (c), 0, 0, 0)

// LDS-only barrier: waits this thread's ds ops, NOT vmem (loads/stores fly).
#define LBAR() {                                                             \
        __builtin_amdgcn_sched_barrier(0);                                   \
        asm volatile("s_waitcnt lgkmcnt(0)" ::: "memory");                   \
        __builtin_amdgcn_s_barrier();                                        \
        __builtin_amdgcn_sched_barrier(0); }

__global__ __launch_bounds__(512, 2) void ComplexMixture_71313636983193_kernel(
    const float* __restrict__ R, const float* __restrict__ I,
    const float* __restrict__ W, float* __restrict__ Or, float* __restrict__ Oi)
{
    // T[0..1] = w*r, w*i (A rows = n-chunk ti)
    // T[2..3] = r, i (B rows = m-chunk tj1);  T[4..5] = r, i (m-chunk tj2)
    // row x, logical chunk c (8 s) at slot c ^ ((x>>1)&7)
    __shared__ alignas(16) _Float16 T[6][64][128];   // 96 KB

    const int pb   = blockIdx.x;
    const int lbid = (pb & 7) * 32 + (pb >> 3);   // 4 batches per XCD
    const int b   = lbid >> 3;
    const int rem = lbid & 7;
    const int ti  = rem >> 1;          // A-side n-chunk
    const int uu  = rem & 1;
    const int tj1 = uu * 2, tj2 = uu * 2 + 1;   // the two B-side m-chunks

    const int t  = threadIdx.x;
    const int wv = t >> 6, lane = t & 63;

    // staging task: 512 = nquad(16) x octet(16) x arr(2)
    const int nquad = t & 15;          // n = nquad*4 + j
    const int octet = (t >> 4) & 15;   // s-octet 0..15 (full K)
    const int arr   = t >> 8;          // 0 = real, 1 = imag (wave-uniform)
    const int s0    = octet * 8;

    const size_t bb = (size_t)b * S * N;
    const float* base  = (arr ? I : R) + bb + nquad * 4;
    const float* srcA  = base + ti  * 64;
    const float* srcB1 = base + tj1 * 64;
    const float* Wb = W + b * S;

    // ---- issue A + B1 loads (8 rows of 4 n each) ----
    float4 fA[8], fB1[8];
    #pragma unroll
    for (int s = 0; s < 8; ++s)
        fA[s] = *(const float4*)&srcA[(size_t)(s0 + s) * N];
    #pragma unroll
    for (int s = 0; s < 8; ++s)
        fB1[s] = *(const float4*)&srcB1[(size_t)(s0 + s) * N];

    float w8[8];
    {
        const float4 a0 = *(const float4*)&Wb[s0];
        const float4 a1 = *(const float4*)&Wb[s0 + 4];
        w8[0]=a0.x; w8[1]=a0.y; w8[2]=a0.z; w8[3]=a0.w;
        w8[4]=a1.x; w8[5]=a1.y; w8[6]=a1.z; w8[7]=a1.w;
    }

    // ---- cvt + write A (weighted) and B1 ----
    #pragma unroll
    for (int j = 0; j < 4; ++j) {
        const int n    = nquad * 4 + j;
        const int slot = octet ^ ((n >> 1) & 7);
        F16x8 fa, fb;
        #pragma unroll
        for (int k = 0; k < 4; ++k) {
            fa.h2[k] = __floats2half2_rn(((const float*)&fA[2*k])[j]   * w8[2*k],
                                         ((const float*)&fA[2*k+1])[j] * w8[2*k+1]);
            fb.h2[k] = __floats2half2_rn(((const float*)&fB1[2*k])[j],
                                         ((const float*)&fB1[2*k+1])[j]);
        }
        *(f16x8*)&T[arr][n][slot * 8]     = fa.v;
        *(f16x8*)&T[2 + arr][n][slot * 8] = fb.v;
    }

    // ---- B2 loads: waves 4-7 only, BOTH arrays (fly across the barrier) ----
    float4 fB2R[8], fB2I[8];
    if (wv >= 4) {
        const float* sR = R + bb + tj2 * 64 + nquad * 4;
        const float* sI = I + bb + tj2 * 64 + nquad * 4;
        #pragma unroll
        for (int s = 0; s < 8; ++s)
            fB2R[s] = *(const float4*)&sR[(size_t)(s0 + s) * N];
        #pragma unroll
        for (int s = 0; s < 8; ++s)
            fB2I[s] = *(const float4*)&sI[(size_t)(s0 + s) * N];
    }

    LBAR();   // A, B1 visible; B2 loads still in flight

    // ---- MFMA geometry: wave owns one 32x32 subtile of its tile ----
    const int sn = (wv >> 1) & 1;      // n sub-block
    const int sm = wv & 1;             // m sub-block
    const int l31 = lane & 31, hi = lane >> 5;
    const int rowA = sn * 32 + l31;    const int sgA = (rowA >> 1) & 7;
    const int rowB = sm * 32 + l31;    const int sgB = (rowB >> 1) & 7;

    f32x16 dR = {0,0,0,0,0,0,0,0,0,0,0,0,0,0,0,0};
    f32x16 dA = {0,0,0,0,0,0,0,0,0,0,0,0,0,0,0,0};
    f32x16 dB = {0,0,0,0,0,0,0,0,0,0,0,0,0,0,0,0};

#define FRAG_STEP(TB, ks) {                                                  \
        const int ca = ((2 * (ks) + hi) ^ sgA) * 8;                          \
        const int cb = ((2 * (ks) + hi) ^ sgB) * 8;                          \
        const f16x8 ar = *(const f16x8*)&T[0][rowA][ca];                     \
        const f16x8 ai = *(const f16x8*)&T[1][rowA][ca];                     \
        const f16x8 br = *(const f16x8*)&T[TB][rowB][cb];                    \
        const f16x8 bi = *(const f16x8*)&T[(TB) + 1][rowB][cb];              \
        dR = MFMA32(ar, br, dR); dR = MFMA32(ai, bi, dR);                    \
        dA = MFMA32(ai, br, dA); dB = MFMA32(ar, bi, dB); }

#define STORE_TILE(TJ) {                                                     \
        const int mm = (TJ) * 64 + sm * 32 + l31;                            \
        _Pragma("unroll")                                                    \
        for (int r = 0; r < 16; ++r) {                                       \
            const int nn = ti * 64 + sn * 32 + (r & 3) + 8 * (r >> 2) + 4 * hi; \
            const size_t o = ((size_t)b * N + nn) * N + mm;                  \
            Or[o] = dR[r];                                                   \
            Oi[o] = dA[r] - dB[r];                                           \
        } }

    if (wv < 4) {
        // ---- tile 1 MFMA (B2 loads + cvt happening on waves 4-7) ----
        __builtin_amdgcn_s_setprio(1);
        FRAG_STEP(2, 0); FRAG_STEP(2, 1); FRAG_STEP(2, 2); FRAG_STEP(2, 3);
        FRAG_STEP(2, 4); FRAG_STEP(2, 5); FRAG_STEP(2, 6); FRAG_STEP(2, 7);
        __builtin_amdgcn_s_setprio(0);
    } else {
        // ---- cvt + write B2 (own buffer; both arrays) ----
        #pragma unroll
        for (int j = 0; j < 4; ++j) {
            const int n    = nquad * 4 + j;
            const int slot = octet ^ ((n >> 1) & 7);
            F16x8 fr, fi;
            #pragma unroll
            for (int k = 0; k < 4; ++k) {
                fr.h2[k] = __floats2half2_rn(((const float*)&fB2R[2*k])[j],
                                             ((const float*)&fB2R[2*k+1])[j]);
                fi.h2[k] = __floats2half2_rn(((const float*)&fB2I[2*k])[j],
                                             ((const float*)&fB2I[2*k+1])[j]);
            }
            *(f16x8*)&T[4][n][slot * 8] = fr.v;
            *(f16x8*)&T[5][n][slot * 8] = fi.v;
        }
    }

    LBAR();   // B2 visible; tile-1 stores not yet issued, B2 regs released

    if (wv < 4) {
        STORE_TILE(tj1);   // drains under tile-2 MFMA on waves 4-7
    } else {
        __builtin_amdgcn_s_setprio(1);
        FRAG_STEP(4, 0); FRAG_STEP(4, 1); FRAG_STEP(4, 2); FRAG_STEP(4, 3);
        FRAG_STEP(4, 4); FRAG_STEP(4, 5); FRAG_STEP(4, 6); FRAG_STEP(4, 7);
        __builtin_amdgcn_s_setprio(0);
        STORE_TILE(tj2);
    }
}

extern "C" void kernel_launch(void* const* d_in, const int* in_sizes, int n_in,
                              void* d_out, int out_size, void* d_ws, size_t ws_size,
                              hipStream_t stream) {
    const float* R = (const float*)d_in[0];
    const float* I = (const float*)d_in[1];
    const float* W = (const float*)d_in[2];
    float* Or = (float*)d_out;
    float* Oi = (float*)d_out + (size_t)B * N * N;

    ComplexMixture_71313636983193_kernel<<<dim3(256), dim3(512), 0, stream>>>(
        R, I, W, Or, Oi);
}